// Round 1
// baseline (97.416 us; speedup 1.0000x reference)
//
#include <hip/hip_runtime.h>

typedef __attribute__((ext_vector_type(8))) short bf16x8;
typedef __attribute__((ext_vector_type(4))) float f32x4;
typedef __attribute__((ext_vector_type(8))) unsigned short us8;
typedef __attribute__((ext_vector_type(4))) unsigned short us4;

#define LOG2E 1.4426950408889634f

__device__ __forceinline__ unsigned short f2bf(float f) {
  union { float f; unsigned u; } v; v.f = f;
  unsigned r = v.u + 0x7fffu + ((v.u >> 16) & 1u);
  return (unsigned short)(r >> 16);
}
__device__ __forceinline__ float fast_tanh(float x) {
  float e = __builtin_amdgcn_exp2f(x * (2.0f * LOG2E));     // e^(2x)
  return 1.0f - 2.0f * __builtin_amdgcn_rcpf(e + 1.0f);
}
__device__ __forceinline__ float fast_sig(float x) {
  return __builtin_amdgcn_rcpf(1.0f + __builtin_amdgcn_exp2f(-LOG2E * x));
}

// Fused: gather(embeddings,con) -> tanh(x@W1+b1) -> tanh(@W2+b2) -> sigmoid(@W3+b3)
// Swapped-operand MFMA: A = transposed-weight frags (registers), B = activation
// frags (LDS, contiguous k), D[n][m] -> contiguous ds_write_b64 epilogues.
__global__ __launch_bounds__(256, 2)
void mlp_fused(const float* __restrict__ con,
               const int* __restrict__ cat2,
               const int* __restrict__ cat3,
               const int* __restrict__ cat4,
               const float* __restrict__ emb2,
               const float* __restrict__ emb3,
               const float* __restrict__ emb4,
               const float* __restrict__ W1, const float* __restrict__ b1,
               const float* __restrict__ W2, const float* __restrict__ b2,
               const float* __restrict__ W3, const float* __restrict__ b3,
               float* __restrict__ out,
               int total_tiles, int tiles_per_block)
{
  __shared__ float embL[112];                 // emb2[0:24) emb3[24:78) emb4[78:110)
  __shared__ unsigned short Xl[64 * 72];      // 64 rows x 64k (+8 pad) bf16
  __shared__ unsigned short H1[64 * 264];     // 64 x 256 (+8)
  __shared__ unsigned short H2[64 * 136];     // 64 x 128 (+8)

  const int t    = threadIdx.x;
  const int wv   = t >> 6;        // wave 0..3
  const int lane = t & 63;
  const int q    = lane >> 4;     // quarter-wave 0..3
  const int r16  = lane & 15;

  // ---- embedding tables -> LDS (once per block)
  if (t < 24)       embL[t] = emb2[t];
  else if (t < 78)  embL[t] = emb3[t - 24];
  else if (t < 110) embL[t] = emb4[t - 78];

  // ---- weight fragments (A-operand, transposed weights), once per block.
  // A-frag layout: lane holds A[n = r16][k = 8*q + j], j=0..7 contiguous.
  bf16x8 w1f[4][2];                 // layer1: this wave's n-range = wv*64 + nf*16
  #pragma unroll
  for (int nf = 0; nf < 4; ++nf) {
    #pragma unroll
    for (int ks = 0; ks < 2; ++ks) {
      const int n = wv * 64 + nf * 16 + r16;
      bf16x8 w;
      #pragma unroll
      for (int j = 0; j < 8; ++j) {
        const int k = ks * 32 + q * 8 + j;     // padded K=64; k==44 is the bias row
        float v = (k < 44) ? W1[k * 256 + n] : ((k == 44) ? b1[n] : 0.f);
        w[j] = (short)f2bf(v);
      }
      w1f[nf][ks] = w;
    }
  }
  bf16x8 w2f[2][8];                 // layer2: n-range = wv*32 + nf*16, K=256
  #pragma unroll
  for (int nf = 0; nf < 2; ++nf) {
    #pragma unroll
    for (int ks = 0; ks < 8; ++ks) {
      const int n = wv * 32 + nf * 16 + r16;
      bf16x8 w;
      #pragma unroll
      for (int j = 0; j < 8; ++j) {
        const int k = ks * 32 + q * 8 + j;
        w[j] = (short)f2bf(W2[k * 128 + n]);
      }
      w2f[nf][ks] = w;
    }
  }
  bf16x8 w3f[4];                    // layer3: N=2 padded to 16, K=128
  #pragma unroll
  for (int ks = 0; ks < 4; ++ks) {
    bf16x8 w;
    #pragma unroll
    for (int j = 0; j < 8; ++j) {
      const int k = ks * 32 + q * 8 + j;
      w[j] = (short)((r16 < 2) ? f2bf(W3[k * 2 + r16]) : (short)0);
    }
    w3f[ks] = w;
  }
  float b2f[2][4];
  #pragma unroll
  for (int nf = 0; nf < 2; ++nf)
    #pragma unroll
    for (int i = 0; i < 4; ++i)
      b2f[nf][i] = b2[wv * 32 + nf * 16 + q * 4 + i];
  const float b3v0 = (q == 0) ? b3[0] : 0.f;
  const float b3v1 = (q == 0) ? b3[1] : 0.f;

  __syncthreads();   // tables ready

  const int tile0 = blockIdx.x * tiles_per_block;
  for (int it = 0; it < tiles_per_block; ++it) {
    const int tile = tile0 + it;
    if (tile >= total_tiles) break;
    const int gbase = tile * 64;

    // ================= gather: wave wv builds k-slice [16*wv, 16*wv+16) ======
    {
      unsigned short f[16];
      const int g = gbase + lane;
      if (wv == 0) {                       // k 0..11: e2 ; k 12..15: e3 tbl0 d0..3
        const int i0 = cat2[g * 3], i1 = cat2[g * 3 + 1], i2 = cat2[g * 3 + 2];
        const int j0 = cat3[g * 3];
        #pragma unroll
        for (int d = 0; d < 4; ++d) {
          f[d]      = f2bf(embL[i0 * 4 + d]);
          f[4 + d]  = f2bf(embL[8 + i1 * 4 + d]);
          f[8 + d]  = f2bf(embL[16 + i2 * 4 + d]);
          f[12 + d] = f2bf(embL[24 + j0 * 6 + d]);
        }
      } else if (wv == 1) {                // k16..29: e3 rest ; k30,31: e4 d0,1
        const int j0 = cat3[g * 3], j1 = cat3[g * 3 + 1], j2 = cat3[g * 3 + 2];
        const int e4 = cat4[g];
        f[0] = f2bf(embL[24 + j0 * 6 + 4]);
        f[1] = f2bf(embL[24 + j0 * 6 + 5]);
        #pragma unroll
        for (int d = 0; d < 6; ++d) {
          f[2 + d] = f2bf(embL[24 + 18 + j1 * 6 + d]);
          f[8 + d] = f2bf(embL[24 + 36 + j2 * 6 + d]);
        }
        f[14] = f2bf(embL[78 + e4 * 8 + 0]);
        f[15] = f2bf(embL[78 + e4 * 8 + 1]);
      } else if (wv == 2) {                // k32..37: e4 d2..7 ; k38..43: con ; k44: 1.0
        const int e4 = cat4[g];
        #pragma unroll
        for (int d = 0; d < 6; ++d) f[d] = f2bf(embL[78 + e4 * 8 + 2 + d]);
        const float2 c0 = *(const float2*)&con[g * 6];
        const float2 c1 = *(const float2*)&con[g * 6 + 2];
        const float2 c2 = *(const float2*)&con[g * 6 + 4];
        f[6] = f2bf(c0.x);  f[7] = f2bf(c0.y);
        f[8] = f2bf(c1.x);  f[9] = f2bf(c1.y);
        f[10] = f2bf(c2.x); f[11] = f2bf(c2.y);
        f[12] = 0x3f80;                    // bf16(1.0) -> picks up b1 row of W1
        f[13] = 0; f[14] = 0; f[15] = 0;
      } else {                             // k48..63: zero pad
        #pragma unroll
        for (int j = 0; j < 16; ++j) f[j] = 0;
      }
      us8 lo, hi;
      #pragma unroll
      for (int j = 0; j < 8; ++j) { lo[j] = f[j]; hi[j] = f[8 + j]; }
      *(us8*)&Xl[lane * 72 + wv * 16]     = lo;
      *(us8*)&Xl[lane * 72 + wv * 16 + 8] = hi;
    }
    __syncthreads();

    // ================= layer 1: h1 = tanh(X @ W1 + b1)  (K=64 padded) ========
    f32x4 acc1[4][4];                      // [nf][mf]
    #pragma unroll
    for (int nf = 0; nf < 4; ++nf)
      #pragma unroll
      for (int mf = 0; mf < 4; ++mf)
        acc1[nf][mf] = (f32x4){0.f, 0.f, 0.f, 0.f};
    #pragma unroll
    for (int ks = 0; ks < 2; ++ks) {
      bf16x8 xb[4];
      #pragma unroll
      for (int mf = 0; mf < 4; ++mf)
        xb[mf] = *(const bf16x8*)&Xl[(mf * 16 + r16) * 72 + ks * 32 + q * 8];
      #pragma unroll
      for (int nf = 0; nf < 4; ++nf)
        #pragma unroll
        for (int mf = 0; mf < 4; ++mf)
          acc1[nf][mf] = __builtin_amdgcn_mfma_f32_16x16x32_bf16(
              w1f[nf][ks], xb[mf], acc1[nf][mf], 0, 0, 0);
    }
    #pragma unroll
    for (int nf = 0; nf < 4; ++nf)
      #pragma unroll
      for (int mf = 0; mf < 4; ++mf) {
        us4 o;
        #pragma unroll
        for (int i = 0; i < 4; ++i) o[i] = f2bf(fast_tanh(acc1[nf][mf][i]));
        *(us4*)&H1[(mf * 16 + r16) * 264 + wv * 64 + nf * 16 + q * 4] = o;
      }
    __syncthreads();

    // ================= layer 2: h2 = tanh(h1 @ W2 + b2)  (K=256) =============
    f32x4 acc2[2][4];
    #pragma unroll
    for (int nf = 0; nf < 2; ++nf)
      #pragma unroll
      for (int mf = 0; mf < 4; ++mf) {
        f32x4 c;
        #pragma unroll
        for (int i = 0; i < 4; ++i) c[i] = b2f[nf][i];
        acc2[nf][mf] = c;
      }
    #pragma unroll
    for (int ks = 0; ks < 8; ++ks) {
      bf16x8 hb[4];
      #pragma unroll
      for (int mf = 0; mf < 4; ++mf)
        hb[mf] = *(const bf16x8*)&H1[(mf * 16 + r16) * 264 + ks * 32 + q * 8];
      #pragma unroll
      for (int nf = 0; nf < 2; ++nf)
        #pragma unroll
        for (int mf = 0; mf < 4; ++mf)
          acc2[nf][mf] = __builtin_amdgcn_mfma_f32_16x16x32_bf16(
              w2f[nf][ks], hb[mf], acc2[nf][mf], 0, 0, 0);
    }
    #pragma unroll
    for (int nf = 0; nf < 2; ++nf)
      #pragma unroll
      for (int mf = 0; mf < 4; ++mf) {
        us4 o;
        #pragma unroll
        for (int i = 0; i < 4; ++i) o[i] = f2bf(fast_tanh(acc2[nf][mf][i]));
        *(us4*)&H2[(mf * 16 + r16) * 136 + wv * 32 + nf * 16 + q * 4] = o;
      }
    __syncthreads();

    // ================= layer 3: out = sigmoid(h2 @ W3 + b3)  (K=128, N=2) ====
    {
      f32x4 acc3;
      acc3[0] = b3v0; acc3[1] = b3v1; acc3[2] = 0.f; acc3[3] = 0.f;
      #pragma unroll
      for (int ks = 0; ks < 4; ++ks) {
        bf16x8 hb = *(const bf16x8*)&H2[(wv * 16 + r16) * 136 + ks * 32 + q * 8];
        acc3 = __builtin_amdgcn_mfma_f32_16x16x32_bf16(w3f[ks], hb, acc3, 0, 0, 0);
      }
      if (q == 0) {                        // lane holds out[n=0,1][m=r16]
        float2 o;
        o.x = fast_sig(acc3[0]);
        o.y = fast_sig(acc3[1]);
        *(float2*)&out[(gbase + wv * 16 + r16) * 2] = o;
      }
    }
    // no barrier needed here: next gather only touches Xl, and the post-gather
    // barrier orders it against this tile's H1/H2 consumers.
  }
}

extern "C" void kernel_launch(void* const* d_in, const int* in_sizes, int n_in,
                              void* d_out, int out_size, void* d_ws, size_t ws_size,
                              hipStream_t stream) {
  (void)d_ws; (void)ws_size; (void)n_in;
  const float* con  = (const float*)d_in[0];
  const int*   cat2 = (const int*)d_in[1];
  const int*   cat3 = (const int*)d_in[2];
  const int*   cat4 = (const int*)d_in[3];
  const float* emb2 = (const float*)d_in[4];
  const float* emb3 = (const float*)d_in[5];
  const float* emb4 = (const float*)d_in[6];
  const float* W1   = (const float*)d_in[7];
  const float* b1   = (const float*)d_in[8];
  const float* W2   = (const float*)d_in[9];
  const float* b2   = (const float*)d_in[10];
  const float* W3   = (const float*)d_in[11];
  const float* b3   = (const float*)d_in[12];
  float* out = (float*)d_out;

  const int rows  = in_sizes[0] / 6;        // B = 524288
  const int tiles = rows / 64;              // 8192
  const int nblocks = 512;
  const int tpb = (tiles + nblocks - 1) / nblocks;   // 16

  hipLaunchKernelGGL(mlp_fused, dim3(nblocks), dim3(256), 0, stream,
                     con, cat2, cat3, cat4, emb2, emb3, emb4,
                     W1, b1, W2, b2, W3, b3, out, tiles, tpb);
}